// Round 1
// baseline (1634.248 us; speedup 1.0000x reference)
//
#include <hip/hip_runtime.h>
#include <math.h>

#define Bb 16
#define Cn 256
#define Cs 32
#define Nn 4096   // 64*64
#define Np 1024   // 32*32
#define Ww 64

// ---------------- weight transpose: w (O x C) -> wT (C x O) ----------------
__global__ void transpose_w(const float* __restrict__ w, float* __restrict__ wT,
                            int O, int C) {
    int idx = blockIdx.x * 256 + threadIdx.x;
    if (idx >= O * C) return;
    int o = idx / C, c = idx - o * C;
    wT[c * O + o] = w[idx];
}

// ---------------- 1x1 conv, channel-major ----------------
// out[b][o0+o][m] = sum_c wT[c][o0+o] * x[b][c][m] + bias[o0+o]
template <int OPB>
__global__ __launch_bounds__(256) void conv1x1_k(
    const float* __restrict__ x, const float* __restrict__ wT,
    const float* __restrict__ bias, float* __restrict__ out, int Cout) {
    int m = blockIdx.x * 256 + threadIdx.x;
    int b = blockIdx.y;
    int o0 = blockIdx.z * OPB;
    const float* xb = x + (size_t)b * Cn * Nn + m;
    float acc[OPB];
#pragma unroll
    for (int o = 0; o < OPB; ++o) acc[o] = 0.f;
#pragma unroll 4
    for (int c = 0; c < Cn; ++c) {
        float xv = xb[(size_t)c * Nn];
        const float* wr = wT + c * Cout + o0;   // uniform -> s_load
#pragma unroll
        for (int o = 0; o < OPB; ++o) acc[o] += wr[o] * xv;
    }
    float* ob = out + ((size_t)b * Cout + o0) * Nn + m;
#pragma unroll
    for (int o = 0; o < OPB; ++o) ob[(size_t)o * Nn] = acc[o] + bias[o0 + o];
}

// ---------------- 2x2 maxpool, channel-major ----------------
__global__ void maxpool2_k(const float* __restrict__ in, float* __restrict__ out,
                           int total) {
    int idx = blockIdx.x * 256 + threadIdx.x;
    if (idx >= total) return;
    int p  = idx & (Np - 1);
    int bc = idx >> 10;
    int ph = p >> 5, pw = p & 31;
    const float* ip = in + (size_t)bc * Nn + (ph * 2) * Ww + pw * 2;
    float v = fmaxf(fmaxf(ip[0], ip[1]), fmaxf(ip[Ww], ip[Ww + 1]));
    out[idx] = v;
}

// ---------------- V' = wo @ Vp, stored transposed: VoT[b][n][o] ----------------
__global__ __launch_bounds__(256) void vo_k(const float* __restrict__ Vp,
                                            const float* __restrict__ woT,
                                            float* __restrict__ VoT) {
    int lane = threadIdx.x & 63;
    int osub = __builtin_amdgcn_readfirstlane(threadIdx.x >> 6);
    int n  = blockIdx.x * 64 + lane;
    int b  = blockIdx.y;
    int o0 = blockIdx.z * 32 + osub * 8;
    const float* vb = Vp + (size_t)b * Cn * Np + n;
    float acc[8];
#pragma unroll
    for (int j = 0; j < 8; ++j) acc[j] = 0.f;
#pragma unroll 4
    for (int c = 0; c < Cn; ++c) {
        float vv = vb[(size_t)c * Np];
        const float* wr = woT + c * Cn + o0;    // uniform -> s_load
#pragma unroll
        for (int j = 0; j < 8; ++j) acc[j] += wr[j] * vv;
    }
    float* op = VoT + ((size_t)b * Np + n) * Cn + o0;
    float4 r0 = make_float4(acc[0], acc[1], acc[2], acc[3]);
    float4 r1 = make_float4(acc[4], acc[5], acc[6], acc[7]);
    *(float4*)op       = r0;
    *(float4*)(op + 4) = r1;
}

// ---------------- per-row softmax stats: max + shifted sum-exp ----------------
// E[n][m] = sum_c Qp[b][c][n] * Kc[b][c][m]; row n over Np, cols m over Nn.
__global__ __launch_bounds__(256) void rowstats_k(
    const float* __restrict__ Kc, const float* __restrict__ Qp,
    float* __restrict__ rmax_g, float* __restrict__ rinv_g) {
    int lane = threadIdx.x & 63;
    int wave = __builtin_amdgcn_readfirstlane(threadIdx.x >> 6);
    int b = blockIdx.y;
    int n = blockIdx.x * 64 + lane;
    const float* Qb = Qp + (size_t)b * Cs * Np + n;
    float q[Cs];
#pragma unroll
    for (int c = 0; c < Cs; ++c) q[c] = Qb[(size_t)c * Np];
    const float* Kb = Kc + (size_t)b * Cs * Nn;
    float rmax = -1e30f, rsum = 0.f;
    int mbase = wave * 1024;
    for (int m = mbase; m < mbase + 1024; m += 4) {
        float e0 = 0.f, e1 = 0.f, e2 = 0.f, e3 = 0.f;
#pragma unroll
        for (int c = 0; c < Cs; ++c) {
            const float* kp = Kb + (size_t)c * Nn + m;  // uniform -> s_load_x4
            float qc = q[c];
            e0 += qc * kp[0]; e1 += qc * kp[1];
            e2 += qc * kp[2]; e3 += qc * kp[3];
        }
        rmax = fmaxf(rmax, fmaxf(fmaxf(e0, e1), fmaxf(e2, e3)));
        rsum += __expf(e0 - 20.f) + __expf(e1 - 20.f) +
                __expf(e2 - 20.f) + __expf(e3 - 20.f);
    }
    __shared__ float sm[4][64];
    __shared__ float ss[4][64];
    sm[wave][lane] = rmax;
    ss[wave][lane] = rsum;
    __syncthreads();
    if (threadIdx.x < 64) {
        float M = fmaxf(fmaxf(sm[0][lane], sm[1][lane]),
                        fmaxf(sm[2][lane], sm[3][lane]));
        float S = ss[0][lane] + ss[1][lane] + ss[2][lane] + ss[3][lane];
        // sum exp(e-M) = S * exp(20-M)  ->  1/sum = exp(M-20)/S
        float rinv = __expf(M - 20.f) / S;
        rmax_g[(size_t)b * Np + n] = M;
        rinv_g[(size_t)b * Np + n] = rinv;
    }
}

// ---------------- fused: recompute E tile -> P (LDS) -> out = g*(V'@P + bo) + x ----
__global__ __launch_bounds__(256) void attn_out_k(
    const float* __restrict__ Kc, const float* __restrict__ Qp,
    const float* __restrict__ VoT, const float* __restrict__ rmax_g,
    const float* __restrict__ rinv_g, const float* __restrict__ bo,
    const float* __restrict__ gamma, const float* __restrict__ x,
    float* __restrict__ out) {
    __shared__ float P[Np * 16];   // 64 KB
    int tid  = threadIdx.x;
    int lane = tid & 63;
    int wave = __builtin_amdgcn_readfirstlane(tid >> 6);
    int b  = blockIdx.y;
    int m0 = blockIdx.x * 16;
    int mt0 = wave * 4;
    const float* Kb  = Kc + (size_t)b * Cs * Nn + m0 + mt0;
    const float* Qb  = Qp + (size_t)b * Cs * Np;
    const float* rmb = rmax_g + (size_t)b * Np;
    const float* rib = rinv_g + (size_t)b * Np;
    // phase 1: each wave computes its 4 m-columns of P for all 1024 rows
    for (int k = 0; k < 16; ++k) {
        int n = k * 64 + lane;
        float e0 = 0.f, e1 = 0.f, e2 = 0.f, e3 = 0.f;
#pragma unroll
        for (int c = 0; c < Cs; ++c) {
            float qv = Qb[(size_t)c * Np + n];          // coalesced
            const float* kp = Kb + (size_t)c * Nn;      // uniform -> s_load
            e0 += qv * kp[0]; e1 += qv * kp[1];
            e2 += qv * kp[2]; e3 += qv * kp[3];
        }
        float M = rmb[n], ri = rib[n];
        float4 p;
        p.x = __expf(e0 - M) * ri;
        p.y = __expf(e1 - M) * ri;
        p.z = __expf(e2 - M) * ri;
        p.w = __expf(e3 - M) * ri;
        *(float4*)&P[n * 16 + mt0] = p;
    }
    __syncthreads();
    // phase 2: thread = output channel c; 16 m's accumulated over 1024 n's
    int c = tid;
    float acc[16];
#pragma unroll
    for (int i = 0; i < 16; ++i) acc[i] = 0.f;
    const float* Vb = VoT + (size_t)b * Np * Cn + c;
#pragma unroll 4
    for (int n = 0; n < Np; ++n) {
        float vv = Vb[(size_t)n * Cn];                  // coalesced over lanes
        const float4 p0 = *(const float4*)&P[n * 16 + 0];
        const float4 p1 = *(const float4*)&P[n * 16 + 4];
        const float4 p2 = *(const float4*)&P[n * 16 + 8];
        const float4 p3 = *(const float4*)&P[n * 16 + 12];
        acc[0]  += vv * p0.x; acc[1]  += vv * p0.y;
        acc[2]  += vv * p0.z; acc[3]  += vv * p0.w;
        acc[4]  += vv * p1.x; acc[5]  += vv * p1.y;
        acc[6]  += vv * p1.z; acc[7]  += vv * p1.w;
        acc[8]  += vv * p2.x; acc[9]  += vv * p2.y;
        acc[10] += vv * p2.z; acc[11] += vv * p2.w;
        acc[12] += vv * p3.x; acc[13] += vv * p3.y;
        acc[14] += vv * p3.z; acc[15] += vv * p3.w;
    }
    float g  = gamma[0];
    float bb = bo[c];
    const float* xb = x   + ((size_t)b * Cn + c) * Nn + m0;
    float*       ob = out + ((size_t)b * Cn + c) * Nn + m0;
#pragma unroll
    for (int v = 0; v < 4; ++v) {
        float4 xv = *(const float4*)&xb[4 * v];
        float4 r;
        r.x = g * (acc[4 * v + 0] + bb) + xv.x;
        r.y = g * (acc[4 * v + 1] + bb) + xv.y;
        r.z = g * (acc[4 * v + 2] + bb) + xv.z;
        r.w = g * (acc[4 * v + 3] + bb) + xv.w;
        *(float4*)&ob[4 * v] = r;
    }
}

extern "C" void kernel_launch(void* const* d_in, const int* in_sizes, int n_in,
                              void* d_out, int out_size, void* d_ws, size_t ws_size,
                              hipStream_t stream) {
    (void)in_sizes; (void)n_in; (void)out_size; (void)ws_size;
    const float* x     = (const float*)d_in[0];
    const float* wq    = (const float*)d_in[1];
    const float* bq    = (const float*)d_in[2];
    const float* wk    = (const float*)d_in[3];
    const float* bk    = (const float*)d_in[4];
    const float* wv    = (const float*)d_in[5];
    const float* bv    = (const float*)d_in[6];
    const float* wo    = (const float*)d_in[7];
    const float* bo    = (const float*)d_in[8];
    const float* gamma = (const float*)d_in[9];
    float* out = (float*)d_out;

    float* ws = (float*)d_ws;
    size_t off = 0;
    float* Kc   = ws + off; off += (size_t)Bb * Cs * Nn;   // 2M
    float* Qf   = ws + off; off += (size_t)Bb * Cs * Nn;   // 2M
    float* Qp   = ws + off; off += (size_t)Bb * Cs * Np;   // 0.5M
    float* Vf   = ws + off; off += (size_t)Bb * Cn * Nn;   // 16.8M
    float* Vp   = ws + off; off += (size_t)Bb * Cn * Np;   // 4.2M
    float* VoT  = ws + off; off += (size_t)Bb * Np * Cn;   // 4.2M
    float* rmax = ws + off; off += (size_t)Bb * Np;
    float* rinv = ws + off; off += (size_t)Bb * Np;
    float* wqT  = ws + off; off += (size_t)Cs * Cn;
    float* wkT  = ws + off; off += (size_t)Cs * Cn;
    float* wvT  = ws + off; off += (size_t)Cn * Cn;
    float* woT  = ws + off; off += (size_t)Cn * Cn;

    // weight transposes
    transpose_w<<<dim3((Cs * Cn + 255) / 256), 256, 0, stream>>>(wq, wqT, Cs, Cn);
    transpose_w<<<dim3((Cs * Cn + 255) / 256), 256, 0, stream>>>(wk, wkT, Cs, Cn);
    transpose_w<<<dim3((Cn * Cn + 255) / 256), 256, 0, stream>>>(wv, wvT, Cn, Cn);
    transpose_w<<<dim3((Cn * Cn + 255) / 256), 256, 0, stream>>>(wo, woT, Cn, Cn);

    // convs (channel-major outputs)
    conv1x1_k<32><<<dim3(Nn / 256, Bb, 1), 256, 0, stream>>>(x, wkT, bk, Kc, Cs);
    conv1x1_k<32><<<dim3(Nn / 256, Bb, 1), 256, 0, stream>>>(x, wqT, bq, Qf, Cs);
    conv1x1_k<64><<<dim3(Nn / 256, Bb, 4), 256, 0, stream>>>(x, wvT, bv, Vf, Cn);

    // pools
    maxpool2_k<<<dim3((Bb * Cs * Np) / 256), 256, 0, stream>>>(Qf, Qp, Bb * Cs * Np);
    maxpool2_k<<<dim3((Bb * Cn * Np) / 256), 256, 0, stream>>>(Vf, Vp, Bb * Cn * Np);

    // V' = wo @ Vp  (transposed store)
    vo_k<<<dim3(Np / 64, Bb, 8), 256, 0, stream>>>(Vp, woT, VoT);

    // softmax row stats
    rowstats_k<<<dim3(Np / 64, Bb), 256, 0, stream>>>(Kc, Qp, rmax, rinv);

    // fused attention output
    attn_out_k<<<dim3(Nn / 16, Bb), 256, 0, stream>>>(Kc, Qp, VoT, rmax, rinv,
                                                      bo, gamma, x, out);
}

// Round 2
// 1119.197 us; speedup vs baseline: 1.4602x; 1.4602x over previous
//
#include <hip/hip_runtime.h>
#include <math.h>

#define Bb 16
#define Cn 256
#define Cs 32
#define Nn 4096   // 64*64
#define Np 1024   // 32*32
#define Ww 64
#define PPAD 8
#define PROW (Np + PPAD)   // bf16 elements per P row (pad -> bank spread)

typedef __attribute__((ext_vector_type(8))) short short8;
typedef __attribute__((ext_vector_type(4))) float f32x4;

__device__ inline short f2bf(float f) {
    unsigned u = __builtin_bit_cast(unsigned, f);
    u += 0x7fff + ((u >> 16) & 1);   // round-to-nearest-even
    return (short)(u >> 16);
}

// ---------------- weight transpose: w (O x C) -> wT (C x O) ----------------
__global__ void transpose_w(const float* __restrict__ w, float* __restrict__ wT,
                            int O, int C) {
    int idx = blockIdx.x * 256 + threadIdx.x;
    if (idx >= O * C) return;
    int o = idx / C, c = idx - o * C;
    wT[c * O + o] = w[idx];
}

// ---------------- 1x1 conv, channel-major ----------------
template <int OPB>
__global__ __launch_bounds__(256) void conv1x1_k(
    const float* __restrict__ x, const float* __restrict__ wT,
    const float* __restrict__ bias, float* __restrict__ out, int Cout) {
    int m = blockIdx.x * 256 + threadIdx.x;
    int b = blockIdx.y;
    int o0 = blockIdx.z * OPB;
    const float* xb = x + (size_t)b * Cn * Nn + m;
    float acc[OPB];
#pragma unroll
    for (int o = 0; o < OPB; ++o) acc[o] = 0.f;
#pragma unroll 4
    for (int c = 0; c < Cn; ++c) {
        float xv = xb[(size_t)c * Nn];
        const float* wr = wT + c * Cout + o0;   // uniform -> s_load
#pragma unroll
        for (int o = 0; o < OPB; ++o) acc[o] += wr[o] * xv;
    }
    float* ob = out + ((size_t)b * Cout + o0) * Nn + m;
#pragma unroll
    for (int o = 0; o < OPB; ++o) ob[(size_t)o * Nn] = acc[o] + bias[o0 + o];
}

// ---------------- 2x2 maxpool, channel-major ----------------
__global__ void maxpool2_k(const float* __restrict__ in, float* __restrict__ out,
                           int total) {
    int idx = blockIdx.x * 256 + threadIdx.x;
    if (idx >= total) return;
    int p  = idx & (Np - 1);
    int bc = idx >> 10;
    int ph = p >> 5, pw = p & 31;
    const float* ip = in + (size_t)bc * Nn + (ph * 2) * Ww + pw * 2;
    float v = fmaxf(fmaxf(ip[0], ip[1]), fmaxf(ip[Ww], ip[Ww + 1]));
    out[idx] = v;
}

// ---------------- V' = wo @ Vp, stored bf16 channel-major: VoBf[b][c][n] ----
__global__ __launch_bounds__(256) void vo_k(const float* __restrict__ Vp,
                                            const float* __restrict__ woT,
                                            short* __restrict__ VoBf) {
    int lane = threadIdx.x & 63;
    int osub = __builtin_amdgcn_readfirstlane(threadIdx.x >> 6);
    int n  = blockIdx.x * 64 + lane;
    int b  = blockIdx.y;
    int o0 = blockIdx.z * 32 + osub * 8;
    const float* vb = Vp + (size_t)b * Cn * Np + n;
    float acc[8];
#pragma unroll
    for (int j = 0; j < 8; ++j) acc[j] = 0.f;
#pragma unroll 4
    for (int c = 0; c < Cn; ++c) {
        float vv = vb[(size_t)c * Np];
        const float* wr = woT + c * Cn + o0;    // uniform -> s_load
#pragma unroll
        for (int j = 0; j < 8; ++j) acc[j] += wr[j] * vv;
    }
    short* op = VoBf + ((size_t)b * Cn + o0) * Np + n;
#pragma unroll
    for (int j = 0; j < 8; ++j) op[(size_t)j * Np] = f2bf(acc[j]);
}

// ---------------- per-row softmax stats: max + shifted sum-exp ----------------
__global__ __launch_bounds__(256) void rowstats_k(
    const float* __restrict__ Kc, const float* __restrict__ Qp,
    float* __restrict__ rmax_g, float* __restrict__ rinv_g) {
    int lane = threadIdx.x & 63;
    int wave = __builtin_amdgcn_readfirstlane(threadIdx.x >> 6);
    int b = blockIdx.y;
    int n = blockIdx.x * 64 + lane;
    const float* Qb = Qp + (size_t)b * Cs * Np + n;
    float q[Cs];
#pragma unroll
    for (int c = 0; c < Cs; ++c) q[c] = Qb[(size_t)c * Np];
    const float* Kb = Kc + (size_t)b * Cs * Nn;
    float rmax = -1e30f, rsum = 0.f;
    int mbase = wave * 1024;
    for (int m = mbase; m < mbase + 1024; m += 4) {
        float e0 = 0.f, e1 = 0.f, e2 = 0.f, e3 = 0.f;
#pragma unroll
        for (int c = 0; c < Cs; ++c) {
            const float* kp = Kb + (size_t)c * Nn + m;  // uniform -> s_load_x4
            float qc = q[c];
            e0 += qc * kp[0]; e1 += qc * kp[1];
            e2 += qc * kp[2]; e3 += qc * kp[3];
        }
        rmax = fmaxf(rmax, fmaxf(fmaxf(e0, e1), fmaxf(e2, e3)));
        rsum += __expf(e0 - 20.f) + __expf(e1 - 20.f) +
                __expf(e2 - 20.f) + __expf(e3 - 20.f);
    }
    __shared__ float sm[4][64];
    __shared__ float ss[4][64];
    sm[wave][lane] = rmax;
    ss[wave][lane] = rsum;
    __syncthreads();
    if (threadIdx.x < 64) {
        float M = fmaxf(fmaxf(sm[0][lane], sm[1][lane]),
                        fmaxf(sm[2][lane], sm[3][lane]));
        float S = ss[0][lane] + ss[1][lane] + ss[2][lane] + ss[3][lane];
        float rinv = __expf(M - 20.f) / S;   // 1/sum(exp(e-M))
        rmax_g[(size_t)b * Np + n] = M;
        rinv_g[(size_t)b * Np + n] = rinv;
    }
}

// ---- fused: E tile -> P (bf16 LDS) -> MFMA: out = g*(V' @ P + bo) + x ------
__global__ __launch_bounds__(256) void attn_out_k(
    const float* __restrict__ Kc, const float* __restrict__ Qp,
    const short* __restrict__ VoBf, const float* __restrict__ rmax_g,
    const float* __restrict__ rinv_g, const float* __restrict__ bo,
    const float* __restrict__ gamma, const float* __restrict__ x,
    float* __restrict__ out) {
    __shared__ short P[16 * PROW];   // 33 KB, P[m_local][n] bf16
    int tid  = threadIdx.x;
    int lane = tid & 63;
    int wave = __builtin_amdgcn_readfirstlane(tid >> 6);
    int b  = blockIdx.y;
    int m0 = blockIdx.x * 16;

    // phase 1: wave owns n-quarter; computes E[n][m0..m0+15], writes P bf16
    const float* Kb  = Kc + (size_t)b * Cs * Nn + m0;   // uniform
    const float* Qb  = Qp + (size_t)b * Cs * Np;
    const float* rmb = rmax_g + (size_t)b * Np;
    const float* rib = rinv_g + (size_t)b * Np;
    int n0 = wave * 256;
    for (int k = 0; k < 4; ++k) {
        int n = n0 + k * 64 + lane;
        float e[16];
#pragma unroll
        for (int m = 0; m < 16; ++m) e[m] = 0.f;
#pragma unroll 4
        for (int c = 0; c < Cs; ++c) {
            float qv = Qb[(size_t)c * Np + n];          // coalesced
            const float* kp = Kb + (size_t)c * Nn;      // uniform -> s_load
#pragma unroll
            for (int m = 0; m < 16; ++m) e[m] += qv * kp[m];
        }
        float M = rmb[n], ri = rib[n];
#pragma unroll
        for (int m = 0; m < 16; ++m)
            P[m * PROW + n] = f2bf(__expf(e[m] - M) * ri);
    }
    __syncthreads();

    // phase 2: MFMA GEMM  out[c][m] = sum_n V'[c][n] * P[n][m]
    int quad = lane >> 4, l16 = lane & 15;
    int c0 = wave * 64;
    const short* Prd = &P[l16 * PROW + quad * 8];
    const short* Vb  = VoBf + ((size_t)b * Cn + c0 + l16) * Np + quad * 8;
    f32x4 acc[4];
#pragma unroll
    for (int s = 0; s < 4; ++s) acc[s] = (f32x4){0.f, 0.f, 0.f, 0.f};
    for (int kk = 0; kk < Np; kk += 32) {
        short8 bfrag = *(const short8*)(Prd + kk);       // B: P[n][m]
#pragma unroll
        for (int s = 0; s < 4; ++s) {
            short8 afrag = *(const short8*)(Vb + (size_t)s * 16 * Np + kk);
            acc[s] = __builtin_amdgcn_mfma_f32_16x16x32_bf16(afrag, bfrag,
                                                             acc[s], 0, 0, 0);
        }
    }
    // epilogue: D row = channel-local, col = m-local
    float g = gamma[0];
#pragma unroll
    for (int s = 0; s < 4; ++s) {
        int cb = c0 + s * 16 + quad * 4;
#pragma unroll
        for (int r = 0; r < 4; ++r) {
            int c = cb + r;
            size_t idx = ((size_t)b * Cn + c) * Nn + m0 + l16;
            out[idx] = g * (acc[s][r] + bo[c]) + x[idx];
        }
    }
}

extern "C" void kernel_launch(void* const* d_in, const int* in_sizes, int n_in,
                              void* d_out, int out_size, void* d_ws, size_t ws_size,
                              hipStream_t stream) {
    (void)in_sizes; (void)n_in; (void)out_size; (void)ws_size;
    const float* x     = (const float*)d_in[0];
    const float* wq    = (const float*)d_in[1];
    const float* bq    = (const float*)d_in[2];
    const float* wk    = (const float*)d_in[3];
    const float* bk    = (const float*)d_in[4];
    const float* wv    = (const float*)d_in[5];
    const float* bv    = (const float*)d_in[6];
    const float* wo    = (const float*)d_in[7];
    const float* bo    = (const float*)d_in[8];
    const float* gamma = (const float*)d_in[9];
    float* out = (float*)d_out;

    float* ws = (float*)d_ws;
    size_t off = 0;
    float* Kc   = ws + off; off += (size_t)Bb * Cs * Nn;   // 2M
    float* Qf   = ws + off; off += (size_t)Bb * Cs * Nn;   // 2M
    float* Qp   = ws + off; off += (size_t)Bb * Cs * Np;   // 0.5M
    float* Vf   = ws + off; off += (size_t)Bb * Cn * Nn;   // 16.8M
    float* Vp   = ws + off; off += (size_t)Bb * Cn * Np;   // 4.2M
    short* VoBf = (short*)(ws + off); off += (size_t)Bb * Cn * Np / 2 + 64;
    float* rmax = ws + off; off += (size_t)Bb * Np;
    float* rinv = ws + off; off += (size_t)Bb * Np;
    float* wqT  = ws + off; off += (size_t)Cs * Cn;
    float* wkT  = ws + off; off += (size_t)Cs * Cn;
    float* wvT  = ws + off; off += (size_t)Cn * Cn;
    float* woT  = ws + off; off += (size_t)Cn * Cn;

    // weight transposes
    transpose_w<<<dim3((Cs * Cn + 255) / 256), 256, 0, stream>>>(wq, wqT, Cs, Cn);
    transpose_w<<<dim3((Cs * Cn + 255) / 256), 256, 0, stream>>>(wk, wkT, Cs, Cn);
    transpose_w<<<dim3((Cn * Cn + 255) / 256), 256, 0, stream>>>(wv, wvT, Cn, Cn);
    transpose_w<<<dim3((Cn * Cn + 255) / 256), 256, 0, stream>>>(wo, woT, Cn, Cn);

    // convs (channel-major outputs)
    conv1x1_k<32><<<dim3(Nn / 256, Bb, 1), 256, 0, stream>>>(x, wkT, bk, Kc, Cs);
    conv1x1_k<32><<<dim3(Nn / 256, Bb, 1), 256, 0, stream>>>(x, wqT, bq, Qf, Cs);
    conv1x1_k<64><<<dim3(Nn / 256, Bb, 4), 256, 0, stream>>>(x, wvT, bv, Vf, Cn);

    // pools
    maxpool2_k<<<dim3((Bb * Cs * Np) / 256), 256, 0, stream>>>(Qf, Qp, Bb * Cs * Np);
    maxpool2_k<<<dim3((Bb * Cn * Np) / 256), 256, 0, stream>>>(Vf, Vp, Bb * Cn * Np);

    // V' = wo @ Vp  (bf16, channel-major)
    vo_k<<<dim3(Np / 64, Bb, 8), 256, 0, stream>>>(Vp, woT, VoBf);

    // softmax row stats
    rowstats_k<<<dim3(Np / 64, Bb), 256, 0, stream>>>(Kc, Qp, rmax, rinv);

    // fused attention output (MFMA)
    attn_out_k<<<dim3(Nn / 16, Bb), 256, 0, stream>>>(Kc, Qp, VoBf, rmax, rinv,
                                                      bo, gamma, x, out);
}

// Round 3
// 650.648 us; speedup vs baseline: 2.5117x; 1.7201x over previous
//
#include <hip/hip_runtime.h>
#include <math.h>

#define Bb 16
#define Cn 256
#define Cs 32
#define Nn 4096   // 64*64
#define Np 1024   // 32*32
#define Ww 64
#define MS 8      // rowstats m-splits

// attn tile params
#define MT 64
#define NT 256
#define PROWB (NT + 8)

typedef __attribute__((ext_vector_type(8))) short short8;
typedef __attribute__((ext_vector_type(4))) float f32x4;

__device__ inline short f2bf(float f) {
    unsigned u = __builtin_bit_cast(unsigned, f);
    u += 0x7fff + ((u >> 16) & 1);   // round-to-nearest-even
    return (short)(u >> 16);
}
__device__ inline float bf2f(short s) {
    unsigned u = ((unsigned)(unsigned short)s) << 16;
    return __builtin_bit_cast(float, u);
}

// ---------------- weight transpose: w (O x C) -> wT (C x O) ----------------
__global__ void transpose_w(const float* __restrict__ w, float* __restrict__ wT,
                            int O, int C) {
    int idx = blockIdx.x * 256 + threadIdx.x;
    if (idx >= O * C) return;
    int o = idx / C, c = idx - o * C;
    wT[c * O + o] = w[idx];
}

// ---------------- f32 -> bf16 elementwise ----------------
__global__ void tobf_k(const float* __restrict__ in, short* __restrict__ out, int n) {
    int idx = blockIdx.x * 256 + threadIdx.x;
    if (idx < n) out[idx] = f2bf(in[idx]);
}

// ---------------- x[b][c][m] f32 -> xbfT[b][m][c] bf16 (LDS transpose) -----
__global__ __launch_bounds__(256) void xpose_bf(const float* __restrict__ x,
                                                short* __restrict__ xbfT) {
    __shared__ float T[64][65];
    int lane = threadIdx.x & 63, g = threadIdx.x >> 6;
    int b = blockIdx.z, c0 = blockIdx.y * 64, m0 = blockIdx.x * 64;
    const float* xb = x + ((size_t)b * Cn + c0) * Nn + m0;
#pragma unroll
    for (int r = 0; r < 16; ++r) {
        int c_l = r * 4 + g;
        T[c_l][lane] = xb[(size_t)c_l * Nn + lane];
    }
    __syncthreads();
    short* ob = xbfT + ((size_t)b * Nn + m0) * Cn + c0;
#pragma unroll
    for (int r = 0; r < 16; ++r) {
        int m_l = r * 4 + g;
        ob[(size_t)m_l * Cn + lane] = f2bf(T[lane][m_l]);
    }
}

// ---------------- 1x1 conv fp32 (Q,K), channel-major ----------------
template <int OPB>
__global__ __launch_bounds__(256) void conv1x1_k(
    const float* __restrict__ x, const float* __restrict__ wT,
    const float* __restrict__ bias, float* __restrict__ out, int Cout) {
    int m = blockIdx.x * 256 + threadIdx.x;
    int b = blockIdx.y;
    int o0 = blockIdx.z * OPB;
    const float* xb = x + (size_t)b * Cn * Nn + m;
    float acc[OPB];
#pragma unroll
    for (int o = 0; o < OPB; ++o) acc[o] = 0.f;
#pragma unroll 4
    for (int c = 0; c < Cn; ++c) {
        float xv = xb[(size_t)c * Nn];
        const float* wr = wT + c * Cout + o0;   // uniform -> s_load
#pragma unroll
        for (int o = 0; o < OPB; ++o) acc[o] += wr[o] * xv;
    }
    float* ob = out + ((size_t)b * Cout + o0) * Nn + m;
#pragma unroll
    for (int o = 0; o < OPB; ++o) ob[(size_t)o * Nn] = acc[o] + bias[o0 + o];
}

// ---------------- V conv via MFMA (no LDS): VfBf[b][o][m] bf16 -------------
__global__ __launch_bounds__(256) void conv_v_mfma(
    const short* __restrict__ xbfT, const short* __restrict__ wvBf,
    const float* __restrict__ bv, short* __restrict__ VfBf) {
    int lane = threadIdx.x & 63;
    int wave = __builtin_amdgcn_readfirstlane(threadIdx.x >> 6);
    int l16 = lane & 15, quad = lane >> 4;
    int b = blockIdx.z;
    int m0 = blockIdx.x * 128 + (wave >> 1) * 64;
    int o0 = blockIdx.y * 128 + (wave & 1) * 64;
    const short* Arow = wvBf + (size_t)(o0 + l16) * Cn + quad * 8;
    const short* Brow = xbfT + ((size_t)b * Nn + m0 + l16) * Cn + quad * 8;
    f32x4 acc[4][4];
#pragma unroll
    for (int i = 0; i < 4; ++i)
#pragma unroll
        for (int j = 0; j < 4; ++j) acc[i][j] = (f32x4){0.f, 0.f, 0.f, 0.f};
    for (int kk = 0; kk < Cn; kk += 32) {
        short8 af[4], bf[4];
#pragma unroll
        for (int fo = 0; fo < 4; ++fo)
            af[fo] = *(const short8*)(Arow + (size_t)(fo * 16) * Cn + kk);
#pragma unroll
        for (int fm = 0; fm < 4; ++fm)
            bf[fm] = *(const short8*)(Brow + (size_t)(fm * 16) * Cn + kk);
#pragma unroll
        for (int fo = 0; fo < 4; ++fo)
#pragma unroll
            for (int fm = 0; fm < 4; ++fm)
                acc[fo][fm] = __builtin_amdgcn_mfma_f32_16x16x32_bf16(
                    af[fo], bf[fm], acc[fo][fm], 0, 0, 0);
    }
#pragma unroll
    for (int fo = 0; fo < 4; ++fo)
#pragma unroll
        for (int fm = 0; fm < 4; ++fm) {
            int m = m0 + fm * 16 + l16;
#pragma unroll
            for (int r = 0; r < 4; ++r) {
                int o = o0 + fo * 16 + quad * 4 + r;
                VfBf[((size_t)b * Cn + o) * Nn + m] = f2bf(acc[fo][fm][r] + bv[o]);
            }
        }
}

// ---------------- 2x2 maxpool fp32 (Q) ----------------
__global__ void maxpool2_k(const float* __restrict__ in, float* __restrict__ out,
                           int total) {
    int idx = blockIdx.x * 256 + threadIdx.x;
    if (idx >= total) return;
    int p  = idx & (Np - 1);
    int bc = idx >> 10;
    int ph = p >> 5, pw = p & 31;
    const float* ip = in + (size_t)bc * Nn + (ph * 2) * Ww + pw * 2;
    out[idx] = fmaxf(fmaxf(ip[0], ip[1]), fmaxf(ip[Ww], ip[Ww + 1]));
}

// ---------------- 2x2 maxpool bf16-in fp32-out (V) ----------------
__global__ void maxpool2_bf(const short* __restrict__ in, float* __restrict__ out,
                            int total) {
    int idx = blockIdx.x * 256 + threadIdx.x;
    if (idx >= total) return;
    int p  = idx & (Np - 1);
    int bc = idx >> 10;
    int ph = p >> 5, pw = p & 31;
    const short* ip = in + (size_t)bc * Nn + (ph * 2) * Ww + pw * 2;
    out[idx] = fmaxf(fmaxf(bf2f(ip[0]), bf2f(ip[1])),
                     fmaxf(bf2f(ip[Ww]), bf2f(ip[Ww + 1])));
}

// ---------------- V' = wo @ Vp, bf16 channel-major: VoBf[b][o][n] ----------
__global__ __launch_bounds__(256) void vo_k(const float* __restrict__ Vp,
                                            const float* __restrict__ woT,
                                            short* __restrict__ VoBf) {
    int lane = threadIdx.x & 63;
    int osub = __builtin_amdgcn_readfirstlane(threadIdx.x >> 6);
    int n  = blockIdx.x * 64 + lane;
    int b  = blockIdx.y;
    int o0 = blockIdx.z * 32 + osub * 8;
    const float* vb = Vp + (size_t)b * Cn * Np + n;
    float acc[8];
#pragma unroll
    for (int j = 0; j < 8; ++j) acc[j] = 0.f;
#pragma unroll 4
    for (int c = 0; c < Cn; ++c) {
        float vv = vb[(size_t)c * Np];
        const float* wr = woT + c * Cn + o0;    // uniform -> s_load
#pragma unroll
        for (int j = 0; j < 8; ++j) acc[j] += wr[j] * vv;
    }
    short* op = VoBf + ((size_t)b * Cn + o0) * Np + n;
#pragma unroll
    for (int j = 0; j < 8; ++j) op[(size_t)j * Np] = f2bf(acc[j]);
}

// ---------------- rowstats partials over m-split ----------------
__global__ __launch_bounds__(256) void rowstats_part(
    const float* __restrict__ Kc, const float* __restrict__ Qp,
    float* __restrict__ pmax, float* __restrict__ psum) {
    int lane = threadIdx.x & 63;
    int wave = __builtin_amdgcn_readfirstlane(threadIdx.x >> 6);
    int b = blockIdx.y;
    int ms = blockIdx.z;
    int n = blockIdx.x * 64 + lane;
    const float* Qb = Qp + (size_t)b * Cs * Np + n;
    float q[Cs];
#pragma unroll
    for (int c = 0; c < Cs; ++c) q[c] = Qb[(size_t)c * Np];
    const float* Kb = Kc + (size_t)b * Cs * Nn;
    float rmax = -1e30f, rsum = 0.f;
    int mbase = ms * (Nn / MS) + wave * (Nn / MS / 4);
    for (int m = mbase; m < mbase + Nn / MS / 4; m += 4) {
        float e0 = 0.f, e1 = 0.f, e2 = 0.f, e3 = 0.f;
#pragma unroll
        for (int c = 0; c < Cs; ++c) {
            const float* kp = Kb + (size_t)c * Nn + m;  // uniform -> s_load
            float qc = q[c];
            e0 += qc * kp[0]; e1 += qc * kp[1];
            e2 += qc * kp[2]; e3 += qc * kp[3];
        }
        rmax = fmaxf(rmax, fmaxf(fmaxf(e0, e1), fmaxf(e2, e3)));
        rsum += __expf(e0 - 20.f) + __expf(e1 - 20.f) +
                __expf(e2 - 20.f) + __expf(e3 - 20.f);
    }
    __shared__ float sm[4][64];
    __shared__ float ss[4][64];
    sm[wave][lane] = rmax;
    ss[wave][lane] = rsum;
    __syncthreads();
    if (threadIdx.x < 64) {
        float M = fmaxf(fmaxf(sm[0][lane], sm[1][lane]),
                        fmaxf(sm[2][lane], sm[3][lane]));
        float S = ss[0][lane] + ss[1][lane] + ss[2][lane] + ss[3][lane];
        size_t o = ((size_t)ms * Bb + b) * Np + n;
        pmax[o] = M;
        psum[o] = S;   // sum of exp(e-20) over this m-range
    }
}

__global__ void rowstats_comb(const float* __restrict__ pmax,
                              const float* __restrict__ psum,
                              float* __restrict__ rmax_g,
                              float* __restrict__ rinv_g) {
    int gidx = blockIdx.x * 256 + threadIdx.x;   // 0..Bb*Np-1
    int b = gidx >> 10, n = gidx & (Np - 1);
    float M = -1e30f, S = 0.f;
#pragma unroll
    for (int ms = 0; ms < MS; ++ms)
        M = fmaxf(M, pmax[((size_t)ms * Bb + b) * Np + n]);
#pragma unroll
    for (int ms = 0; ms < MS; ++ms)
        S += psum[((size_t)ms * Bb + b) * Np + n];
    rmax_g[(size_t)b * Np + n] = M;
    rinv_g[(size_t)b * Np + n] = __expf(M - 20.f) / S;
}

// ---- fused: E (64-m tile) -> P bf16 LDS (256-n sub-tiles) -> MFMA out -----
__global__ __launch_bounds__(256) void attn_out_k(
    const float* __restrict__ Kc, const float* __restrict__ Qp,
    const short* __restrict__ VoBf, const float* __restrict__ rmax_g,
    const float* __restrict__ rinv_g, const float* __restrict__ bo,
    const float* __restrict__ gamma, const float* __restrict__ x,
    float* __restrict__ out) {
    __shared__ short P[MT * PROWB];   // P[m_local][n_local], ~33 KB
    int tid  = threadIdx.x;
    int lane = tid & 63;
    int wave = __builtin_amdgcn_readfirstlane(tid >> 6);
    int l16 = lane & 15, quad = lane >> 4;
    int b  = blockIdx.y;
    int m0 = blockIdx.x * MT;

    const float* Kb  = Kc + (size_t)b * Cs * Nn + m0;
    const float* Qb  = Qp + (size_t)b * Cs * Np;
    const float* rmb = rmax_g + (size_t)b * Np;
    const float* rib = rinv_g + (size_t)b * Np;
    int o_w = wave * 64;
    const short* Arow = VoBf + ((size_t)b * Cn + o_w + l16) * Np + quad * 8;

    f32x4 acc[4][4];
#pragma unroll
    for (int i = 0; i < 4; ++i)
#pragma unroll
        for (int j = 0; j < 4; ++j) acc[i][j] = (f32x4){0.f, 0.f, 0.f, 0.f};

    int n_l = wave * 64 + lane;          // 0..255 within n-tile
    for (int t = 0; t < 4; ++t) {
        // phase 1: each lane owns one n; computes E[n][m0..m0+63] -> P
        int n = t * NT + n_l;
        float e[MT];
#pragma unroll
        for (int m = 0; m < MT; ++m) e[m] = 0.f;
        for (int c = 0; c < Cs; ++c) {
            float qv = Qb[(size_t)c * Np + n];          // coalesced
            const float* kp = Kb + (size_t)c * Nn;      // uniform -> s_load
#pragma unroll
            for (int m = 0; m < MT; ++m) e[m] += qv * kp[m];
        }
        float M = rmb[n], ri = rib[n];
#pragma unroll
        for (int m = 0; m < MT; ++m)
            P[m * PROWB + n_l] = f2bf(__expf(e[m] - M) * ri);
        __syncthreads();
        // phase 2: MFMA over this n-tile; wave = 64-o strip
        const short* At = Arow + t * NT;
        for (int kk = 0; kk < NT; kk += 32) {
            short8 bfr[4], afr[4];
#pragma unroll
            for (int fm = 0; fm < 4; ++fm)
                bfr[fm] = *(const short8*)&P[(fm * 16 + l16) * PROWB + kk + quad * 8];
#pragma unroll
            for (int fo = 0; fo < 4; ++fo)
                afr[fo] = *(const short8*)(At + (size_t)(fo * 16) * Np + kk);
#pragma unroll
            for (int fo = 0; fo < 4; ++fo)
#pragma unroll
                for (int fm = 0; fm < 4; ++fm)
                    acc[fo][fm] = __builtin_amdgcn_mfma_f32_16x16x32_bf16(
                        afr[fo], bfr[fm], acc[fo][fm], 0, 0, 0);
        }
        __syncthreads();
    }
    // epilogue
    float g = gamma[0];
#pragma unroll
    for (int fo = 0; fo < 4; ++fo)
#pragma unroll
        for (int fm = 0; fm < 4; ++fm) {
            int m = m0 + fm * 16 + l16;
#pragma unroll
            for (int r = 0; r < 4; ++r) {
                int o = o_w + fo * 16 + quad * 4 + r;
                size_t idx = ((size_t)b * Cn + o) * Nn + m;
                out[idx] = g * (acc[fo][fm][r] + bo[o]) + x[idx];
            }
        }
}

extern "C" void kernel_launch(void* const* d_in, const int* in_sizes, int n_in,
                              void* d_out, int out_size, void* d_ws, size_t ws_size,
                              hipStream_t stream) {
    (void)in_sizes; (void)n_in; (void)out_size; (void)ws_size;
    const float* x     = (const float*)d_in[0];
    const float* wq    = (const float*)d_in[1];
    const float* bq    = (const float*)d_in[2];
    const float* wk    = (const float*)d_in[3];
    const float* bk    = (const float*)d_in[4];
    const float* wv    = (const float*)d_in[5];
    const float* bv    = (const float*)d_in[6];
    const float* wo    = (const float*)d_in[7];
    const float* bo    = (const float*)d_in[8];
    const float* gamma = (const float*)d_in[9];
    float* out = (float*)d_out;

    float* ws = (float*)d_ws;
    size_t off = 0;
    float* Kc   = ws + off; off += (size_t)Bb * Cs * Nn;        // 2.10M
    float* Qf   = ws + off; off += (size_t)Bb * Cs * Nn;        // 2.10M
    float* Qp   = ws + off; off += (size_t)Bb * Cs * Np;        // 0.52M
    float* Vp   = ws + off; off += (size_t)Bb * Cn * Np;        // 4.19M
    short* VfBf = (short*)(ws + off); off += (size_t)Bb * Cn * Nn / 2;  // 8.39M
    short* VoBf = (short*)(ws + off); off += (size_t)Bb * Cn * Np / 2;  // 2.10M
    short* xbfT = (short*)(ws + off); off += (size_t)Bb * Nn * Cn / 2;  // 8.39M
    short* wvBf = (short*)(ws + off); off += (size_t)Cn * Cn / 2;
    float* rmax = ws + off; off += (size_t)Bb * Np;
    float* rinv = ws + off; off += (size_t)Bb * Np;
    float* pmax = ws + off; off += (size_t)MS * Bb * Np;
    float* psum = ws + off; off += (size_t)MS * Bb * Np;
    float* wqT  = ws + off; off += (size_t)Cs * Cn;
    float* wkT  = ws + off; off += (size_t)Cs * Cn;
    float* woT  = ws + off; off += (size_t)Cn * Cn;

    // weight prep
    transpose_w<<<dim3((Cs * Cn + 255) / 256), 256, 0, stream>>>(wq, wqT, Cs, Cn);
    transpose_w<<<dim3((Cs * Cn + 255) / 256), 256, 0, stream>>>(wk, wkT, Cs, Cn);
    transpose_w<<<dim3((Cn * Cn + 255) / 256), 256, 0, stream>>>(wo, woT, Cn, Cn);
    tobf_k<<<dim3(Cn * Cn / 256), 256, 0, stream>>>(wv, wvBf, Cn * Cn);

    // x -> bf16 transposed [b][m][c]
    xpose_bf<<<dim3(Nn / 64, Cn / 64, Bb), 256, 0, stream>>>(x, xbfT);

    // Q/K convs fp32 (z-split for occupancy)
    conv1x1_k<16><<<dim3(Nn / 256, Bb, 2), 256, 0, stream>>>(x, wkT, bk, Kc, Cs);
    conv1x1_k<16><<<dim3(Nn / 256, Bb, 2), 256, 0, stream>>>(x, wqT, bq, Qf, Cs);

    // V conv via MFMA
    conv_v_mfma<<<dim3(Nn / 128, Cn / 128, Bb), 256, 0, stream>>>(xbfT, wvBf, bv, VfBf);

    // pools
    maxpool2_k<<<dim3((Bb * Cs * Np) / 256), 256, 0, stream>>>(Qf, Qp, Bb * Cs * Np);
    maxpool2_bf<<<dim3((Bb * Cn * Np) / 256), 256, 0, stream>>>(VfBf, Vp, Bb * Cn * Np);

    // V' = wo @ Vp  (bf16, channel-major)
    vo_k<<<dim3(Np / 64, Bb, 8), 256, 0, stream>>>(Vp, woT, VoBf);

    // softmax row stats (m-split + combine)
    rowstats_part<<<dim3(Np / 64, Bb, MS), 256, 0, stream>>>(Kc, Qp, pmax, psum);
    rowstats_comb<<<dim3(Bb * Np / 256), 256, 0, stream>>>(pmax, psum, rmax, rinv);

    // fused attention output (MFMA)
    attn_out_k<<<dim3(Nn / MT, Bb), 256, 0, stream>>>(Kc, Qp, VoBf, rmax, rinv,
                                                      bo, gamma, x, out);
}

// Round 6
// 400.041 us; speedup vs baseline: 4.0852x; 1.6265x over previous
//
#include <hip/hip_runtime.h>
#include <math.h>

#define Bb 16
#define Cn 256
#define Cs 32
#define Nn 4096   // 64*64
#define Np 1024   // 32*32
#define Ww 64
#define MS2 8     // rowstats m-splits

// attn tile params
#define MT 64
#define NT 256
#define PRN (NT + 8)   // shorts per m-row of P in LDS

typedef __attribute__((ext_vector_type(8))) short short8;
typedef __attribute__((ext_vector_type(4))) float f32x4;

__device__ inline short f2bf(float f) {
    unsigned u = __builtin_bit_cast(unsigned, f);
    u += 0x7fff + ((u >> 16) & 1);   // round-to-nearest-even
    return (short)(u >> 16);
}
__device__ inline float bf2f(short s) {
    unsigned u = ((unsigned)(unsigned short)s) << 16;
    return __builtin_bit_cast(float, u);
}

// ---------------- weight transpose: w (O x C) -> wT (C x O) ----------------
__global__ void transpose_w(const float* __restrict__ w, float* __restrict__ wT,
                            int O, int C) {
    int idx = blockIdx.x * 256 + threadIdx.x;
    if (idx >= O * C) return;
    int o = idx / C, c = idx - o * C;
    wT[c * O + o] = w[idx];
}

// ---------------- f32 -> bf16 elementwise ----------------
__global__ void tobf_k(const float* __restrict__ in, short* __restrict__ out, int n) {
    int idx = blockIdx.x * 256 + threadIdx.x;
    if (idx < n) out[idx] = f2bf(in[idx]);
}

// ---------------- x[b][c][m] f32 -> xbfT[b][m][c] bf16 (LDS transpose) -----
__global__ __launch_bounds__(256) void xpose_bf(const float* __restrict__ x,
                                                short* __restrict__ xbfT) {
    __shared__ float T[64][65];
    int lane = threadIdx.x & 63, g = threadIdx.x >> 6;
    int b = blockIdx.z, c0 = blockIdx.y * 64, m0 = blockIdx.x * 64;
    const float* xb = x + ((size_t)b * Cn + c0) * Nn + m0;
#pragma unroll
    for (int r = 0; r < 16; ++r) {
        int c_l = r * 4 + g;
        T[c_l][lane] = xb[(size_t)c_l * Nn + lane];
    }
    __syncthreads();
    short* ob = xbfT + ((size_t)b * Nn + m0) * Cn + c0;
#pragma unroll
    for (int r = 0; r < 16; ++r) {
        int m_l = r * 4 + g;
        ob[(size_t)m_l * Cn + lane] = f2bf(T[lane][m_l]);
    }
}

// ------ fused Q/K conv: x once -> QfT[b][m][c], KT[b][m][c] bf16 -----------
__global__ __launch_bounds__(256) void conv_qk(
    const float* __restrict__ x, const float* __restrict__ wqT,
    const float* __restrict__ wkT, const float* __restrict__ bq,
    const float* __restrict__ bk, short* __restrict__ QfT,
    short* __restrict__ KT) {
    int m = blockIdx.x * 256 + threadIdx.x;
    int b = blockIdx.y;
    int o0 = blockIdx.z * 16;     // z in {0,1}
    const float* xb = x + (size_t)b * Cn * Nn + m;
    float qa[16], ka[16];
#pragma unroll
    for (int j = 0; j < 16; ++j) { qa[j] = 0.f; ka[j] = 0.f; }
#pragma unroll 4
    for (int c = 0; c < Cn; ++c) {
        float xv = xb[(size_t)c * Nn];
        const float* wqr = wqT + c * Cs + o0;   // uniform -> s_load
        const float* wkr = wkT + c * Cs + o0;
#pragma unroll
        for (int j = 0; j < 16; ++j) {
            qa[j] += wqr[j] * xv;
            ka[j] += wkr[j] * xv;
        }
    }
    short8 qv0, qv1, kv0, kv1;
#pragma unroll
    for (int j = 0; j < 8; ++j) {
        qv0[j] = f2bf(qa[j] + bq[o0 + j]);
        qv1[j] = f2bf(qa[8 + j] + bq[o0 + 8 + j]);
        kv0[j] = f2bf(ka[j] + bk[o0 + j]);
        kv1[j] = f2bf(ka[8 + j] + bk[o0 + 8 + j]);
    }
    short* qp = QfT + ((size_t)b * Nn + m) * Cs + o0;
    short* kp = KT  + ((size_t)b * Nn + m) * Cs + o0;
    *(short8*)qp = qv0; *(short8*)(qp + 8) = qv1;
    *(short8*)kp = kv0; *(short8*)(kp + 8) = kv1;
}

// ---------------- Q pool: QfT[b][m][32] -> QpT[b][n][32], bf16 -------------
__global__ void pool_q(const short* __restrict__ QfT, short* __restrict__ QpT) {
    int idx = blockIdx.x * 256 + threadIdx.x;   // Bb*Np*16 dword-slots
    int c2 = idx & 15;
    int n  = (idx >> 4) & (Np - 1);
    int b  = idx >> 14;
    int ph = n >> 5, pw = n & 31;
    int m00 = (ph * 2) * Ww + pw * 2;
    const unsigned* base = (const unsigned*)QfT + (size_t)b * Nn * 16;
    unsigned u0 = base[(size_t)(m00) * 16 + c2];
    unsigned u1 = base[(size_t)(m00 + 1) * 16 + c2];
    unsigned u2 = base[(size_t)(m00 + Ww) * 16 + c2];
    unsigned u3 = base[(size_t)(m00 + Ww + 1) * 16 + c2];
    float l = fmaxf(fmaxf(__builtin_bit_cast(float, u0 << 16),
                          __builtin_bit_cast(float, u1 << 16)),
                    fmaxf(__builtin_bit_cast(float, u2 << 16),
                          __builtin_bit_cast(float, u3 << 16)));
    float h = fmaxf(fmaxf(__builtin_bit_cast(float, u0 & 0xffff0000u),
                          __builtin_bit_cast(float, u1 & 0xffff0000u)),
                    fmaxf(__builtin_bit_cast(float, u2 & 0xffff0000u),
                          __builtin_bit_cast(float, u3 & 0xffff0000u)));
    unsigned r = (__builtin_bit_cast(unsigned, h) & 0xffff0000u) |
                 (__builtin_bit_cast(unsigned, l) >> 16);
    ((unsigned*)QpT)[((size_t)b * Np + n) * 16 + c2] = r;
}

// ---------------- V conv via MFMA (no LDS): VfBf[b][o][m] bf16 -------------
__global__ __launch_bounds__(256) void conv_v_mfma(
    const short* __restrict__ xbfT, const short* __restrict__ wvBf,
    const float* __restrict__ bv, short* __restrict__ VfBf) {
    int lane = threadIdx.x & 63;
    int wave = __builtin_amdgcn_readfirstlane(threadIdx.x >> 6);
    int l16 = lane & 15, quad = lane >> 4;
    int b = blockIdx.z;
    int m0 = blockIdx.x * 128 + (wave >> 1) * 64;
    int o0 = blockIdx.y * 128 + (wave & 1) * 64;
    const short* Arow = wvBf + (size_t)(o0 + l16) * Cn + quad * 8;
    const short* Brow = xbfT + ((size_t)b * Nn + m0 + l16) * Cn + quad * 8;
    f32x4 acc[4][4];
#pragma unroll
    for (int i = 0; i < 4; ++i)
#pragma unroll
        for (int j = 0; j < 4; ++j) acc[i][j] = (f32x4){0.f, 0.f, 0.f, 0.f};
    for (int kk = 0; kk < Cn; kk += 32) {
        short8 af[4], bf[4];
#pragma unroll
        for (int fo = 0; fo < 4; ++fo)
            af[fo] = *(const short8*)(Arow + (size_t)(fo * 16) * Cn + kk);
#pragma unroll
        for (int fm = 0; fm < 4; ++fm)
            bf[fm] = *(const short8*)(Brow + (size_t)(fm * 16) * Cn + kk);
#pragma unroll
        for (int fo = 0; fo < 4; ++fo)
#pragma unroll
            for (int fm = 0; fm < 4; ++fm)
                acc[fo][fm] = __builtin_amdgcn_mfma_f32_16x16x32_bf16(
                    af[fo], bf[fm], acc[fo][fm], 0, 0, 0);
    }
#pragma unroll
    for (int fo = 0; fo < 4; ++fo)
#pragma unroll
        for (int fm = 0; fm < 4; ++fm) {
            int m = m0 + fm * 16 + l16;
#pragma unroll
            for (int r = 0; r < 4; ++r) {
                int o = o0 + fo * 16 + quad * 4 + r;
                VfBf[((size_t)b * Cn + o) * Nn + m] = f2bf(acc[fo][fm][r] + bv[o]);
            }
        }
}

// ---------------- 2x2 maxpool bf16-in fp32-out (V) ----------------
__global__ void maxpool2_bf(const short* __restrict__ in, float* __restrict__ out,
                            int total) {
    int idx = blockIdx.x * 256 + threadIdx.x;
    if (idx >= total) return;
    int p  = idx & (Np - 1);
    int bc = idx >> 10;
    int ph = p >> 5, pw = p & 31;
    const short* ip = in + (size_t)bc * Nn + (ph * 2) * Ww + pw * 2;
    out[idx] = fmaxf(fmaxf(bf2f(ip[0]), bf2f(ip[1])),
                     fmaxf(bf2f(ip[Ww]), bf2f(ip[Ww + 1])));
}

// ---- V' = wo @ Vp, bf16 channel-major: VoBf[b][o][n] (round-3 form) -------
__global__ __launch_bounds__(256) void vo_k(const float* __restrict__ Vp,
                                            const float* __restrict__ woT,
                                            short* __restrict__ VoBf) {
    int lane = threadIdx.x & 63;
    int osub = __builtin_amdgcn_readfirstlane(threadIdx.x >> 6);
    int n  = blockIdx.x * 64 + lane;
    int b  = blockIdx.y;
    int o0 = blockIdx.z * 32 + osub * 8;
    const float* vb = Vp + (size_t)b * Cn * Np + n;
    float acc[8];
#pragma unroll
    for (int j = 0; j < 8; ++j) acc[j] = 0.f;
#pragma unroll 4
    for (int c = 0; c < Cn; ++c) {
        float vv = vb[(size_t)c * Np];
        const float* wr = woT + c * Cn + o0;    // uniform -> s_load
#pragma unroll
        for (int j = 0; j < 8; ++j) acc[j] += wr[j] * vv;
    }
    short* op = VoBf + ((size_t)b * Cn + o0) * Np + n;
#pragma unroll
    for (int j = 0; j < 8; ++j) op[(size_t)j * Np] = f2bf(acc[j]);
}

// ---- rowstats: per-row online max + sum-exp partials via MFMA -------------
__global__ __launch_bounds__(256) void rowstats_mfma(
    const short* __restrict__ KT, const short* __restrict__ QpT,
    float* __restrict__ pM, float* __restrict__ pS) {
    int lane = threadIdx.x & 63;
    int wave = __builtin_amdgcn_readfirstlane(threadIdx.x >> 6);
    int l16 = lane & 15, quad = lane >> 4;
    int b = blockIdx.y, ms = blockIdx.z;
    int nbase = blockIdx.x * 256 + wave * 64;
    short8 af[4];
#pragma unroll
    for (int nf = 0; nf < 4; ++nf)
        af[nf] = *(const short8*)(QpT +
            ((size_t)b * Np + nbase + nf * 16 + l16) * Cs + quad * 8);
    float Mv[4][4], Sv[4][4];
#pragma unroll
    for (int nf = 0; nf < 4; ++nf)
#pragma unroll
        for (int r = 0; r < 4; ++r) { Mv[nf][r] = -1e30f; Sv[nf][r] = 0.f; }
    int m0 = ms * (Nn / MS2);
    for (int mm = 0; mm < Nn / MS2; mm += 16) {
        short8 bf = *(const short8*)(KT +
            ((size_t)b * Nn + m0 + mm + l16) * Cs + quad * 8);
#pragma unroll
        for (int nf = 0; nf < 4; ++nf) {
            f32x4 e = __builtin_amdgcn_mfma_f32_16x16x32_bf16(
                af[nf], bf, (f32x4){0.f, 0.f, 0.f, 0.f}, 0, 0, 0);
#pragma unroll
            for (int r = 0; r < 4; ++r) {
                float Mn = fmaxf(Mv[nf][r], e[r]);
                Sv[nf][r] = Sv[nf][r] * __expf(Mv[nf][r] - Mn) +
                            __expf(e[r] - Mn);
                Mv[nf][r] = Mn;
            }
        }
    }
    // merge across the 16 lanes (l16) that hold disjoint m-slices of row n
#pragma unroll
    for (int nf = 0; nf < 4; ++nf)
#pragma unroll
        for (int r = 0; r < 4; ++r) {
            float M = Mv[nf][r], S = Sv[nf][r];
#pragma unroll
            for (int s = 1; s <= 8; s <<= 1) {
                float Mo = __shfl_xor(M, s);
                float So = __shfl_xor(S, s);
                float Mn = fmaxf(M, Mo);
                S = S * __expf(M - Mn) + So * __expf(Mo - Mn);
                M = Mn;
            }
            Mv[nf][r] = M; Sv[nf][r] = S;
        }
    if (l16 == 0) {
#pragma unroll
        for (int nf = 0; nf < 4; ++nf)
#pragma unroll
            for (int r = 0; r < 4; ++r) {
                size_t o = ((size_t)ms * Bb + b) * Np + nbase + nf * 16 +
                           quad * 4 + r;
                pM[o] = Mv[nf][r];
                pS[o] = Sv[nf][r];
            }
    }
}

// ---- combine partials -> Mri[b][n] = (M, 1/S) -----------------------------
__global__ void comb_k(const float* __restrict__ pM, const float* __restrict__ pS,
                       float2* __restrict__ Mri) {
    int gidx = blockIdx.x * 256 + threadIdx.x;   // Bb*Np
    int b = gidx >> 10, n = gidx & (Np - 1);
    float M = -1e30f, S = 0.f;
#pragma unroll
    for (int ms = 0; ms < MS2; ++ms) {
        size_t o = ((size_t)ms * Bb + b) * Np + n;
        float Mo = pM[o], So = pS[o];
        float Mn = fmaxf(M, Mo);
        S = S * __expf(M - Mn) + So * __expf(Mo - Mn);
        M = Mn;
    }
    Mri[(size_t)b * Np + n] = make_float2(M, 1.f / S);
}

// ---- fused: energy MFMA -> softmax (bounded) -> P bf16 LDS -> PV MFMA -----
__global__ __launch_bounds__(256) void attn_out_k(
    const short* __restrict__ KT, const short* __restrict__ QpT,
    const short* __restrict__ VoBf, const float2* __restrict__ Mri,
    const float* __restrict__ bo, const float* __restrict__ gamma,
    const float* __restrict__ x, float* __restrict__ out) {
    __shared__ short P[MT * PRN];   // P[m_local][n_sub], 33.8 KB
    int tid  = threadIdx.x;
    int lane = tid & 63;
    int wave = __builtin_amdgcn_readfirstlane(tid >> 6);
    int l16 = lane & 15, quad = lane >> 4;
    int b  = blockIdx.y;
    int m0 = blockIdx.x * MT;

    const short* QT = QpT + (size_t)b * Np * Cs;
    const short* Kb = KT + ((size_t)b * Nn + m0) * Cs;
    const short* Vb = VoBf + ((size_t)b * Cn + wave * 64) * Np;
    const float2* Mb = Mri + (size_t)b * Np;

    // K m-strip fragments constant across subtiles — hoist
    short8 kf[4];
#pragma unroll
    for (int mf = 0; mf < 4; ++mf)
        kf[mf] = *(const short8*)(Kb + (size_t)(mf * 16 + l16) * Cs + quad * 8);

    f32x4 acc[4][4];
#pragma unroll
    for (int i = 0; i < 4; ++i)
#pragma unroll
        for (int j = 0; j < 4; ++j) acc[i][j] = (f32x4){0.f, 0.f, 0.f, 0.f};

    for (int t = 0; t < 4; ++t) {
        int nb = t * NT + wave * 64;
        // per-row (M, 1/S) for the 16 rows this lane produces
        float2 mr[4][4];
#pragma unroll
        for (int nf = 0; nf < 4; ++nf)
#pragma unroll
            for (int r = 0; r < 4; ++r)
                mr[nf][r] = Mb[nb + nf * 16 + quad * 4 + r];
        // ---- energy phase: wave owns n-strip wave*64 within subtile ----
#pragma unroll
        for (int nf = 0; nf < 4; ++nf) {
            short8 qf = *(const short8*)(QT +
                (size_t)(nb + nf * 16 + l16) * Cs + quad * 8);
#pragma unroll
            for (int mf = 0; mf < 4; ++mf) {
                f32x4 e = __builtin_amdgcn_mfma_f32_16x16x32_bf16(
                    qf, kf[mf], (f32x4){0.f, 0.f, 0.f, 0.f}, 0, 0, 0);
                float p0 = __expf(e[0] - mr[nf][0].x) * mr[nf][0].y;
                float p1 = __expf(e[1] - mr[nf][1].x) * mr[nf][1].y;
                float p2 = __expf(e[2] - mr[nf][2].x) * mr[nf][2].y;
                float p3 = __expf(e[3] - mr[nf][3].x) * mr[nf][3].y;
                unsigned p01 = ((unsigned)(unsigned short)f2bf(p1) << 16) |
                               (unsigned short)f2bf(p0);
                unsigned p23 = ((unsigned)(unsigned short)f2bf(p3) << 16) |
                               (unsigned short)f2bf(p2);
                int m_l = mf * 16 + l16;
                int n_l = wave * 64 + nf * 16 + quad * 4;
                *(uint2*)&P[m_l * PRN + n_l] = make_uint2(p01, p23);
            }
        }
        __syncthreads();
        // ---- PV phase: wave owns c-strip wave*64 ----
        const short* At = Vb + t * NT;
        for (int kk = 0; kk < NT; kk += 32) {
            short8 bfr[4], afr[4];
#pragma unroll
            for (int fm = 0; fm < 4; ++fm)
                bfr[fm] = *(const short8*)&P[(fm * 16 + l16) * PRN + kk + quad * 8];
#pragma unroll
            for (int fo = 0; fo < 4; ++fo)
                afr[fo] = *(const short8*)(At + (size_t)(fo * 16 + l16) * Np +
                                           kk + quad * 8);   // FIX: + quad*8
#pragma unroll
            for (int fo = 0; fo < 4; ++fo)
#pragma unroll
                for (int fm = 0; fm < 4; ++fm)
                    acc[fo][fm] = __builtin_amdgcn_mfma_f32_16x16x32_bf16(
                        afr[fo], bfr[fm], acc[fo][fm], 0, 0, 0);
        }
        __syncthreads();
    }
    // ---- epilogue ----
    float g = gamma[0];
#pragma unroll
    for (int fo = 0; fo < 4; ++fo)
#pragma unroll
        for (int fm = 0; fm < 4; ++fm) {
            int m = m0 + fm * 16 + l16;
#pragma unroll
            for (int r = 0; r < 4; ++r) {
                int o = wave * 64 + fo * 16 + quad * 4 + r;
                size_t idx = ((size_t)b * Cn + o) * Nn + m;
                out[idx] = g * (acc[fo][fm][r] + bo[o]) + x[idx];
            }
        }
}

extern "C" void kernel_launch(void* const* d_in, const int* in_sizes, int n_in,
                              void* d_out, int out_size, void* d_ws, size_t ws_size,
                              hipStream_t stream) {
    (void)in_sizes; (void)n_in; (void)out_size; (void)ws_size;
    const float* x     = (const float*)d_in[0];
    const float* wq    = (const float*)d_in[1];
    const float* bq    = (const float*)d_in[2];
    const float* wk    = (const float*)d_in[3];
    const float* bk    = (const float*)d_in[4];
    const float* wv    = (const float*)d_in[5];
    const float* bv    = (const float*)d_in[6];
    const float* wo    = (const float*)d_in[7];
    const float* bo    = (const float*)d_in[8];
    const float* gamma = (const float*)d_in[9];
    float* out = (float*)d_out;

    float* ws = (float*)d_ws;
    size_t off = 0;
    short* xbfT = (short*)(ws + off); off += (size_t)Bb * Nn * Cn / 2;  // 33.5MB
    short* VfBf = (short*)(ws + off); off += (size_t)Bb * Cn * Nn / 2;  // 33.5MB
    float* Vp   = ws + off;           off += (size_t)Bb * Cn * Np;      // 16.8MB
    short* VoBf = (short*)(ws + off); off += (size_t)Bb * Cn * Np / 2;  //  8.4MB
    short* KT   = (short*)(ws + off); off += (size_t)Bb * Nn * Cs / 2;  //  4.2MB
    short* QfT  = (short*)(ws + off); off += (size_t)Bb * Nn * Cs / 2;  //  4.2MB
    short* QpT  = (short*)(ws + off); off += (size_t)Bb * Np * Cs / 2;  //  1.0MB
    float* pM   = ws + off;           off += (size_t)MS2 * Bb * Np;
    float* pS   = ws + off;           off += (size_t)MS2 * Bb * Np;
    float2* Mri = (float2*)(ws + off); off += (size_t)2 * Bb * Np;
    float* wqT  = ws + off;           off += (size_t)Cs * Cn;
    float* wkT  = ws + off;           off += (size_t)Cs * Cn;
    float* woT  = ws + off;           off += (size_t)Cn * Cn;
    short* wvBf = (short*)(ws + off); off += (size_t)Cn * Cn / 2;

    // weight prep
    transpose_w<<<dim3((Cs * Cn + 255) / 256), 256, 0, stream>>>(wq, wqT, Cs, Cn);
    transpose_w<<<dim3((Cs * Cn + 255) / 256), 256, 0, stream>>>(wk, wkT, Cs, Cn);
    transpose_w<<<dim3((Cn * Cn + 255) / 256), 256, 0, stream>>>(wo, woT, Cn, Cn);
    tobf_k<<<dim3(Cn * Cn / 256), 256, 0, stream>>>(wv, wvBf, Cn * Cn);

    // x -> bf16 transposed [b][m][c]
    xpose_bf<<<dim3(Nn / 64, Cn / 64, Bb), 256, 0, stream>>>(x, xbfT);

    // fused Q/K conv -> bf16 [m][c]
    conv_qk<<<dim3(Nn / 256, Bb, 2), 256, 0, stream>>>(x, wqT, wkT, bq, bk, QfT, KT);

    // Q pool -> QpT[b][n][c]
    pool_q<<<dim3(Bb * Np * 16 / 256), 256, 0, stream>>>(QfT, QpT);

    // V conv via MFMA, then pool
    conv_v_mfma<<<dim3(Nn / 128, Cn / 128, Bb), 256, 0, stream>>>(xbfT, wvBf, bv, VfBf);
    maxpool2_bf<<<dim3((Bb * Cn * Np) / 256), 256, 0, stream>>>(VfBf, Vp, Bb * Cn * Np);

    // softmax row stats: online max+sum (MFMA energies)
    rowstats_mfma<<<dim3(Np / 256, Bb, MS2), 256, 0, stream>>>(KT, QpT, pM, pS);
    comb_k<<<dim3(Bb * Np / 256), 256, 0, stream>>>(pM, pS, Mri);

    // V' = wo @ Vp (bf16, channel-major) — round-3-validated form
    vo_k<<<dim3(Np / 64, Bb, 8), 256, 0, stream>>>(Vp, woT, VoBf);

    // fused attention output (all-MFMA, bounded softmax)
    attn_out_k<<<dim3(Nn / MT, Bb), 256, 0, stream>>>(KT, QpT, VoBf, Mri,
                                                      bo, gamma, x, out);
}